// Round 2
// baseline (5942.496 us; speedup 1.0000x reference)
//
#include <hip/hip_runtime.h>
#include <hip/hip_bf16.h>
#include <math.h>

#define S_ 2048
#define SE_ 2048
#define D_ 1024
#define H_ 8
#define DK_ 128
#define FF_ 4096
#define QB 16

// ---------------------------------------------------------------------------
// Tiled fp32 GEMM: C[M,N] = A[M,K] @ B[K,N] + bias, optional ReLU.
// Batched via blockIdx.z with element strides sA/sB/sBias/sC.
// All dims assumed multiples of tile sizes (true for this problem).
// ---------------------------------------------------------------------------
__global__ __launch_bounds__(256) void gemm_kernel(
    const float* __restrict__ A, const float* __restrict__ B,
    const float* __restrict__ bias, float* __restrict__ C,
    int M, int N, int K, int lda, int ldb, int ldc,
    long sA, long sB, long sBias, long sC, int relu)
{
    const int bz = blockIdx.z;
    A += (long)bz * sA;
    B += (long)bz * sB;
    C += (long)bz * sC;
    const float* biasp = bias + (long)bz * sBias;

    __shared__ float As[16][65];   // [k][m]
    __shared__ float Bs[16][65];   // [k][n]

    const int tid = threadIdx.x;
    const int tx = tid & 15;        // 0..15 -> cols
    const int ty = tid >> 4;        // 0..15 -> rows
    const int rowBase = blockIdx.y * 64;
    const int colBase = blockIdx.x * 64;

    const int akk = tid & 15;       // k for A loads
    const int am  = tid >> 4;       // m (0..15), +16 steps
    const int bn  = tid & 63;       // n for B loads
    const int bk0 = tid >> 6;       // 0..3, +4 steps

    float acc[4][4] = {{0.f,0.f,0.f,0.f},{0.f,0.f,0.f,0.f},
                       {0.f,0.f,0.f,0.f},{0.f,0.f,0.f,0.f}};

    for (int k0 = 0; k0 < K; k0 += 16) {
#pragma unroll
        for (int j = 0; j < 4; ++j) {
            As[akk][am + j*16] =
                A[(long)(rowBase + am + j*16) * lda + (k0 + akk)];
            Bs[bk0 + j*4][bn] =
                B[(long)(k0 + bk0 + j*4) * ldb + (colBase + bn)];
        }
        __syncthreads();
#pragma unroll
        for (int kk = 0; kk < 16; ++kk) {
            float a0 = As[kk][ty*4+0];
            float a1 = As[kk][ty*4+1];
            float a2 = As[kk][ty*4+2];
            float a3 = As[kk][ty*4+3];
            float b0 = Bs[kk][tx*4+0];
            float b1 = Bs[kk][tx*4+1];
            float b2 = Bs[kk][tx*4+2];
            float b3 = Bs[kk][tx*4+3];
            acc[0][0] += a0*b0; acc[0][1] += a0*b1; acc[0][2] += a0*b2; acc[0][3] += a0*b3;
            acc[1][0] += a1*b0; acc[1][1] += a1*b1; acc[1][2] += a1*b2; acc[1][3] += a1*b3;
            acc[2][0] += a2*b0; acc[2][1] += a2*b1; acc[2][2] += a2*b2; acc[2][3] += a2*b3;
            acc[3][0] += a3*b0; acc[3][1] += a3*b1; acc[3][2] += a3*b2; acc[3][3] += a3*b3;
        }
        __syncthreads();
    }

#pragma unroll
    for (int i = 0; i < 4; ++i) {
        const int r = rowBase + ty*4 + i;
#pragma unroll
        for (int j = 0; j < 4; ++j) {
            const int c = colBase + tx*4 + j;
            float v = acc[i][j] + biasp[c];
            if (relu) v = fmaxf(v, 0.f);
            C[(long)r * ldc + c] = v;
        }
    }
}

// ---------------------------------------------------------------------------
// Fused attention: one block per (head, 16-row query block).
// Q/K/V are [H][S][128] (f32). Output written in concat-heads layout
// O[s][h*128 + d]. Scores strip QB x T lives in LDS.
// scores = (Q.K^T)/1024 (note: /D, NOT /sqrt(D), per reference).
// ---------------------------------------------------------------------------
__global__ __launch_bounds__(256) void attn_kernel(
    const float* __restrict__ Q, const float* __restrict__ Km,
    const float* __restrict__ Vm, float* __restrict__ O,
    int T, int masked)
{
    const int h  = blockIdx.y;
    const int s0 = blockIdx.x * QB;
    const int tid = threadIdx.x;

    __shared__ float sc[QB][2048];
    __shared__ float qs[QB][128];
    __shared__ float red[256];

    const float* Qh = Q  + ((long)h * S_ + s0) * 128;
    const float* Kh = Km + (long)h * T * 128;
    const float* Vh = Vm + (long)h * T * 128;

    for (int i = tid; i < QB*128; i += 256) qs[i>>7][i&127] = Qh[i];
    __syncthreads();

    const int Tlim = masked ? (s0 + QB) : T;
    const float scale = 1.0f / 1024.0f;

    // ---- scores ----
    for (int r = 0; r < QB; ++r) {
        const int rowT = masked ? (s0 + r + 1) : T;  // # valid keys for this row
        for (int t = tid; t < Tlim; t += 256) {
            float val = -INFINITY;
            if (t < rowT) {
                const float* kp = Kh + (long)t * 128;
                float acc = 0.f;
#pragma unroll
                for (int d = 0; d < 128; d += 4) {
                    float4 kv = *reinterpret_cast<const float4*>(kp + d);
                    acc += qs[r][d+0]*kv.x + qs[r][d+1]*kv.y
                         + qs[r][d+2]*kv.z + qs[r][d+3]*kv.w;
                }
                val = acc * scale;
            }
            sc[r][t] = val;
        }
    }
    __syncthreads();

    // ---- softmax per row ----
    for (int r = 0; r < QB; ++r) {
        float m = -INFINITY;
        for (int t = tid; t < Tlim; t += 256) m = fmaxf(m, sc[r][t]);
        red[tid] = m; __syncthreads();
#pragma unroll
        for (int off = 128; off > 0; off >>= 1) {
            if (tid < off) red[tid] = fmaxf(red[tid], red[tid+off]);
            __syncthreads();
        }
        m = red[0]; __syncthreads();

        float s = 0.f;
        for (int t = tid; t < Tlim; t += 256) {
            float e = __expf(sc[r][t] - m);
            sc[r][t] = e;
            s += e;
        }
        red[tid] = s; __syncthreads();
#pragma unroll
        for (int off = 128; off > 0; off >>= 1) {
            if (tid < off) red[tid] += red[tid+off];
            __syncthreads();
        }
        s = red[0]; __syncthreads();

        const float inv = 1.0f / s;
        for (int t = tid; t < Tlim; t += 256) sc[r][t] *= inv;
    }
    __syncthreads();

    // ---- A @ V ----
    const int d  = tid & 127;
    const int hi = tid >> 7;     // 0 or 1
    float acc[8] = {0,0,0,0,0,0,0,0};
    for (int t = 0; t < Tlim; ++t) {
        const float v = Vh[(long)t*128 + d];
#pragma unroll
        for (int j = 0; j < 8; ++j) acc[j] += sc[2*j + hi][t] * v;
    }
#pragma unroll
    for (int j = 0; j < 8; ++j) {
        const int r = 2*j + hi;
        O[(long)(s0 + r) * (H_*DK_) + h*DK_ + d] = acc[j];
    }
}

// ---------------------------------------------------------------------------
// out[row] = LayerNorm(X[row] + Y[row]) * gamma + beta ; D = 1024
// ---------------------------------------------------------------------------
__global__ __launch_bounds__(256) void add_ln_kernel(
    const float* __restrict__ X, const float* __restrict__ Y,
    const float* __restrict__ gamma, const float* __restrict__ beta,
    float* __restrict__ Out)
{
    const int row = blockIdx.x;
    const int tid = threadIdx.x;
    __shared__ float red[256];

    const float* xr = X + (long)row * D_;
    const float* yr = Y + (long)row * D_;

    float v[4];
    float s = 0.f;
#pragma unroll
    for (int j = 0; j < 4; ++j) {
        v[j] = xr[tid + j*256] + yr[tid + j*256];
        s += v[j];
    }
    red[tid] = s; __syncthreads();
#pragma unroll
    for (int off = 128; off > 0; off >>= 1) {
        if (tid < off) red[tid] += red[tid+off];
        __syncthreads();
    }
    const float mean = red[0] * (1.0f / D_);
    __syncthreads();

    float s2 = 0.f;
#pragma unroll
    for (int j = 0; j < 4; ++j) { float dd = v[j] - mean; s2 += dd*dd; }
    red[tid] = s2; __syncthreads();
#pragma unroll
    for (int off = 128; off > 0; off >>= 1) {
        if (tid < off) red[tid] += red[tid+off];
        __syncthreads();
    }
    const float var = red[0] * (1.0f / D_);
    const float rs = rsqrtf(var + 1e-5f);

#pragma unroll
    for (int j = 0; j < 4; ++j) {
        const int c = tid + j*256;
        Out[(long)row * D_ + c] = (v[j] - mean) * rs * gamma[c] + beta[c];
    }
}

// ---------------------------------------------------------------------------
extern "C" void kernel_launch(void* const* d_in, const int* in_sizes, int n_in,
                              void* d_out, int out_size, void* d_ws, size_t ws_size,
                              hipStream_t stream)
{
    const int LAYER = 5;  // only the last layer's output survives (x=decoderInput bug)

    const float* decIn  = (const float*)d_in[0];
    const float* encOut = (const float*)d_in[1];
    const float* Wq1 = (const float*)d_in[2]  + (long)LAYER * H_ * D_ * DK_;
    const float* bq1 = (const float*)d_in[3]  + (long)LAYER * H_ * DK_;
    const float* Wk1 = (const float*)d_in[4]  + (long)LAYER * H_ * D_ * DK_;
    const float* bk1 = (const float*)d_in[5]  + (long)LAYER * H_ * DK_;
    const float* Wv1 = (const float*)d_in[6]  + (long)LAYER * H_ * D_ * DK_;
    const float* bv1 = (const float*)d_in[7]  + (long)LAYER * H_ * DK_;
    const float* Wq2 = (const float*)d_in[8]  + (long)LAYER * H_ * D_ * DK_;
    const float* bq2 = (const float*)d_in[9]  + (long)LAYER * H_ * DK_;
    const float* Wk2 = (const float*)d_in[10] + (long)LAYER * H_ * D_ * DK_;
    const float* bk2 = (const float*)d_in[11] + (long)LAYER * H_ * DK_;
    const float* Wv2 = (const float*)d_in[12] + (long)LAYER * H_ * D_ * DK_;
    const float* bv2 = (const float*)d_in[13] + (long)LAYER * H_ * DK_;
    const float* Wff1 = (const float*)d_in[14] + (long)LAYER * D_ * FF_;
    const float* bff1 = (const float*)d_in[15] + (long)LAYER * FF_;
    const float* Wff2 = (const float*)d_in[16] + (long)LAYER * FF_ * D_;
    const float* bff2 = (const float*)d_in[17] + (long)LAYER * D_;
    const float* gamma = (const float*)d_in[18];
    const float* beta  = (const float*)d_in[19];

    float* ws = (float*)d_ws;
    const long nQ = (long)H_ * S_ * DK_;     // 2M elems
    float* Qb   = ws;            ws += nQ;
    float* Kb   = ws;            ws += nQ;
    float* Vb   = ws;            ws += nQ;
    float* attn = ws;            ws += (long)S_ * D_;
    float* h1   = ws;            ws += (long)S_ * D_;
    float* h2   = ws;            ws += (long)S_ * D_;
    float* ffh  = ws;            ws += (long)S_ * FF_;
    float* ff2  = ws;            ws += (long)S_ * D_;

    float* outp = (float*)d_out;
    const dim3 blk(256);

    // ---------------- self attention (masked) ----------------
    // Q/K/V projections: batched over heads; A = decIn (stride 0 across batch)
    {
        dim3 grid(DK_/64, S_/64, H_);
        gemm_kernel<<<grid, blk, 0, stream>>>(decIn, Wq1, bq1, Qb,
            S_, DK_, D_, D_, DK_, DK_, 0L, (long)D_*DK_, (long)DK_, (long)S_*DK_, 0);
        gemm_kernel<<<grid, blk, 0, stream>>>(decIn, Wk1, bk1, Kb,
            S_, DK_, D_, D_, DK_, DK_, 0L, (long)D_*DK_, (long)DK_, (long)S_*DK_, 0);
        gemm_kernel<<<grid, blk, 0, stream>>>(decIn, Wv1, bv1, Vb,
            S_, DK_, D_, D_, DK_, DK_, 0L, (long)D_*DK_, (long)DK_, (long)S_*DK_, 0);
    }
    attn_kernel<<<dim3(S_/QB, H_), blk, 0, stream>>>(Qb, Kb, Vb, attn, S_, 1);
    add_ln_kernel<<<dim3(S_), blk, 0, stream>>>(decIn, attn, gamma, beta, h1);

    // ---------------- cross attention (unmasked) ----------------
    {
        dim3 grid(DK_/64, S_/64, H_);
        gemm_kernel<<<grid, blk, 0, stream>>>(h1, Wq2, bq2, Qb,
            S_, DK_, D_, D_, DK_, DK_, 0L, (long)D_*DK_, (long)DK_, (long)S_*DK_, 0);
        dim3 gridE(DK_/64, SE_/64, H_);
        gemm_kernel<<<gridE, blk, 0, stream>>>(encOut, Wk2, bk2, Kb,
            SE_, DK_, D_, D_, DK_, DK_, 0L, (long)D_*DK_, (long)DK_, (long)SE_*DK_, 0);
        gemm_kernel<<<gridE, blk, 0, stream>>>(encOut, Wv2, bv2, Vb,
            SE_, DK_, D_, D_, DK_, DK_, 0L, (long)D_*DK_, (long)DK_, (long)SE_*DK_, 0);
    }
    attn_kernel<<<dim3(S_/QB, H_), blk, 0, stream>>>(Qb, Kb, Vb, attn, SE_, 0);
    add_ln_kernel<<<dim3(S_), blk, 0, stream>>>(h1, attn, gamma, beta, h2);

    // ---------------- feed-forward ----------------
    gemm_kernel<<<dim3(FF_/64, S_/64, 1), blk, 0, stream>>>(h2, Wff1, bff1, ffh,
        S_, FF_, D_, D_, FF_, FF_, 0L, 0L, 0L, 0L, 1);
    gemm_kernel<<<dim3(D_/64, S_/64, 1), blk, 0, stream>>>(ffh, Wff2, bff2, ff2,
        S_, D_, FF_, FF_, D_, D_, 0L, 0L, 0L, 0L, 0);

    add_ln_kernel<<<dim3(S_), blk, 0, stream>>>(h2, ff2, gamma, beta, outp);
}

// Round 3
// 1931.608 us; speedup vs baseline: 3.0765x; 3.0765x over previous
//
#include <hip/hip_runtime.h>
#include <hip/hip_bf16.h>
#include <math.h>

#define S_ 2048
#define SE_ 2048
#define D_ 1024
#define H_ 8
#define DK_ 128
#define FF_ 4096

typedef short bf16x8 __attribute__((ext_vector_type(8)));
typedef float f32x4 __attribute__((ext_vector_type(4)));

// ---------------------------------------------------------------------------
// Tiled fp32 GEMM: C[M,N] = A[M,K] @ B[K,N] + bias, optional ReLU.
// mode: 0 = f32 store C[r*ldc+c]; 1 = bf16 store C[r*ldc+c];
//       2 = bf16 TRANSPOSED store C[c*ldc + r]   (for V^T)
// ---------------------------------------------------------------------------
__global__ __launch_bounds__(256) void gemm_kernel(
    const float* __restrict__ A, const float* __restrict__ B,
    const float* __restrict__ bias, void* __restrict__ C,
    int M, int N, int K, int lda, int ldb, int ldc,
    long sA, long sB, long sBias, long sC, int relu, int mode)
{
    const int bz = blockIdx.z;
    A += (long)bz * sA;
    B += (long)bz * sB;
    const float* biasp = bias + (long)bz * sBias;

    __shared__ float As[16][65];   // [k][m]
    __shared__ float Bs[16][65];   // [k][n]

    const int tid = threadIdx.x;
    const int tx = tid & 15;
    const int ty = tid >> 4;
    const int rowBase = blockIdx.y * 64;
    const int colBase = blockIdx.x * 64;

    const int akk = tid & 15;
    const int am  = tid >> 4;
    const int bn  = tid & 63;
    const int bk0 = tid >> 6;

    float acc[4][4] = {{0.f,0.f,0.f,0.f},{0.f,0.f,0.f,0.f},
                       {0.f,0.f,0.f,0.f},{0.f,0.f,0.f,0.f}};

    for (int k0 = 0; k0 < K; k0 += 16) {
#pragma unroll
        for (int j = 0; j < 4; ++j) {
            As[akk][am + j*16] =
                A[(long)(rowBase + am + j*16) * lda + (k0 + akk)];
            Bs[bk0 + j*4][bn] =
                B[(long)(k0 + bk0 + j*4) * ldb + (colBase + bn)];
        }
        __syncthreads();
#pragma unroll
        for (int kk = 0; kk < 16; ++kk) {
            float a0 = As[kk][ty*4+0];
            float a1 = As[kk][ty*4+1];
            float a2 = As[kk][ty*4+2];
            float a3 = As[kk][ty*4+3];
            float b0 = Bs[kk][tx*4+0];
            float b1 = Bs[kk][tx*4+1];
            float b2 = Bs[kk][tx*4+2];
            float b3 = Bs[kk][tx*4+3];
            acc[0][0] += a0*b0; acc[0][1] += a0*b1; acc[0][2] += a0*b2; acc[0][3] += a0*b3;
            acc[1][0] += a1*b0; acc[1][1] += a1*b1; acc[1][2] += a1*b2; acc[1][3] += a1*b3;
            acc[2][0] += a2*b0; acc[2][1] += a2*b1; acc[2][2] += a2*b2; acc[2][3] += a2*b3;
            acc[3][0] += a3*b0; acc[3][1] += a3*b1; acc[3][2] += a3*b2; acc[3][3] += a3*b3;
        }
        __syncthreads();
    }

#pragma unroll
    for (int i = 0; i < 4; ++i) {
        const int r = rowBase + ty*4 + i;
#pragma unroll
        for (int j = 0; j < 4; ++j) {
            const int c = colBase + tx*4 + j;
            float v = acc[i][j] + biasp[c];
            if (relu) v = fmaxf(v, 0.f);
            if (mode == 0) {
                ((float*)C)[(long)bz * sC + (long)r * ldc + c] = v;
            } else if (mode == 1) {
                ((__hip_bfloat16*)C)[(long)bz * sC + (long)r * ldc + c] =
                    __float2bfloat16(v);
            } else {
                ((__hip_bfloat16*)C)[(long)bz * sC + (long)c * ldc + r] =
                    __float2bfloat16(v);
            }
        }
    }
}

// ---------------------------------------------------------------------------
// MFMA flash attention.
// Q: [H][S][128] bf16 (row-major), K: [H][T][128] bf16, Vt: [H][128][T] bf16.
// O: [S][H*128] f32 (concat heads). scores = (Q.K^T)/1024 (per reference!).
// Block = 128 threads = 2 waves; each wave owns 16 query rows.
// Per 32-key chunk: QK^T via 8 mfma, online softmax in D-layout regs,
// P routed through a 16x32 LDS tile (D-layout -> A-layout transpose),
// PV via 8 mfma into 8 f32x4 accumulators (128 v-cols).
// K/V fragments for chunk i+1 are prefetched during chunk i (1 wave/SIMD:
// no TLP, so ILP prefetch is required).
// mfma_f32_16x16x32_bf16 layouts (verified m89/m92):
//   A[m][k]: m=lane&15, k=8*(lane>>4)+j ;  B[k][n]: n=lane&15, k=8*(lane>>4)+j
//   D[m][n]: n=lane&15, m=4*(lane>>4)+reg
// ---------------------------------------------------------------------------
__global__ __launch_bounds__(128) void mfma_attn_kernel(
    const __hip_bfloat16* __restrict__ Q, const __hip_bfloat16* __restrict__ K,
    const __hip_bfloat16* __restrict__ Vt, float* __restrict__ O,
    int T, int masked)
{
    const int h    = blockIdx.y;
    const int w    = threadIdx.x >> 6;
    const int lane = threadIdx.x & 63;
    const int n    = lane & 15;
    const int g    = lane >> 4;
    const int qw   = blockIdx.x * 32 + w * 16;   // first query row of this wave

    __shared__ short P_lds[2][16][40];   // [wave][q][t], stride 40 shorts (80B)

    const __hip_bfloat16* Qh = Q  + (long)h * S_ * DK_;
    const __hip_bfloat16* Kh = K  + (long)h * (long)T * DK_;
    const __hip_bfloat16* Vh = Vt + (long)h * DK_ * (long)T;

    // Q fragments (held for whole kernel): rows qw..qw+15, K=128 in 4 chunks
    bf16x8 qf[4];
#pragma unroll
    for (int kc = 0; kc < 4; ++kc)
        qf[kc] = *reinterpret_cast<const bf16x8*>(
            Qh + (long)(qw + n) * DK_ + kc * 32 + g * 8);

    f32x4 o[8];
#pragma unroll
    for (int vt = 0; vt < 8; ++vt) o[vt] = f32x4{0.f, 0.f, 0.f, 0.f};
    float mrow[4] = {-INFINITY, -INFINITY, -INFINITY, -INFINITY};
    float lrow[4] = {0.f, 0.f, 0.f, 0.f};

    const int nch = masked ? ((qw + 47) >> 5) : (T >> 5);

    // preload chunk 0 fragments
    bf16x8 kf[2][4], vf[8];
#pragma unroll
    for (int tt = 0; tt < 2; ++tt)
#pragma unroll
        for (int kc = 0; kc < 4; ++kc)
            kf[tt][kc] = *reinterpret_cast<const bf16x8*>(
                Kh + (long)(tt * 16 + n) * DK_ + kc * 32 + g * 8);
#pragma unroll
    for (int vt = 0; vt < 8; ++vt)
        vf[vt] = *reinterpret_cast<const bf16x8*>(
            Vh + (long)(vt * 16 + n) * T + g * 8);

    for (int i = 0; i < nch; ++i) {
        const int t0 = i * 32;
        const int t1 = (i + 1 < nch) ? (t0 + 32) : t0;   // next-chunk base (clamped)

        // ---- QK^T: two 16-col tiles, K=128 over 4 mfma each ----
        f32x4 s0 = {0.f, 0.f, 0.f, 0.f}, s1 = {0.f, 0.f, 0.f, 0.f};
#pragma unroll
        for (int kc = 0; kc < 4; ++kc) {
            s0 = __builtin_amdgcn_mfma_f32_16x16x32_bf16(qf[kc], kf[0][kc], s0, 0, 0, 0);
            s1 = __builtin_amdgcn_mfma_f32_16x16x32_bf16(qf[kc], kf[1][kc], s1, 0, 0, 0);
        }

        // ---- prefetch next K (covered by softmax+PV below) ----
#pragma unroll
        for (int tt = 0; tt < 2; ++tt)
#pragma unroll
            for (int kc = 0; kc < 4; ++kc)
                kf[tt][kc] = *reinterpret_cast<const bf16x8*>(
                    Kh + (long)(t1 + tt * 16 + n) * DK_ + kc * 32 + g * 8);

        // ---- online softmax (scores scaled by 1/D) ----
        const bool needmask = masked && (t0 + 31 > qw);
        float corr[4];
#pragma unroll
        for (int r = 0; r < 4; ++r) {
            float a = s0[r] * (1.0f / 1024.0f);
            float b = s1[r] * (1.0f / 1024.0f);
            if (needmask) {
                const int qg = qw + 4 * g + r;
                if (t0 + n > qg)      a = -INFINITY;
                if (t0 + 16 + n > qg) b = -INFINITY;
            }
            float mx = fmaxf(a, b);
            mx = fmaxf(mx, __shfl_xor(mx, 1));
            mx = fmaxf(mx, __shfl_xor(mx, 2));
            mx = fmaxf(mx, __shfl_xor(mx, 4));
            mx = fmaxf(mx, __shfl_xor(mx, 8));
            const float mnew = fmaxf(mrow[r], mx);
            const float c  = __expf(mrow[r] - mnew);   // -inf -> 0 on first chunk
            const float pa = __expf(a - mnew);
            const float pb = __expf(b - mnew);
            float rs = pa + pb;
            rs += __shfl_xor(rs, 1);
            rs += __shfl_xor(rs, 2);
            rs += __shfl_xor(rs, 4);
            rs += __shfl_xor(rs, 8);
            lrow[r] = lrow[r] * c + rs;
            mrow[r] = mnew;
            corr[r] = c;
            __hip_bfloat16 ha = __float2bfloat16(pa);
            __hip_bfloat16 hb = __float2bfloat16(pb);
            P_lds[w][4 * g + r][n]      = *reinterpret_cast<short*>(&ha);
            P_lds[w][4 * g + r][16 + n] = *reinterpret_cast<short*>(&hb);
        }

        // ---- rescale O accumulators ----
#pragma unroll
        for (int vt = 0; vt < 8; ++vt)
#pragma unroll
            for (int r = 0; r < 4; ++r) o[vt][r] *= corr[r];

        // ---- PV: P tile (A-layout via LDS) x V chunks ----
        bf16x8 pfrag = *reinterpret_cast<const bf16x8*>(&P_lds[w][n][g * 8]);
#pragma unroll
        for (int vt = 0; vt < 8; ++vt)
            o[vt] = __builtin_amdgcn_mfma_f32_16x16x32_bf16(pfrag, vf[vt], o[vt], 0, 0, 0);

        // ---- prefetch next V (covered by next chunk's QK^T+softmax) ----
#pragma unroll
        for (int vt = 0; vt < 8; ++vt)
            vf[vt] = *reinterpret_cast<const bf16x8*>(
                Vh + (long)(vt * 16 + n) * T + t1 + g * 8);
    }

    // ---- epilogue: O = acc / l, concat-heads layout ----
#pragma unroll
    for (int vt = 0; vt < 8; ++vt)
#pragma unroll
        for (int r = 0; r < 4; ++r)
            O[(long)(qw + 4 * g + r) * (H_ * DK_) + h * DK_ + vt * 16 + n] =
                o[vt][r] / lrow[r];
}

// ---------------------------------------------------------------------------
// out[row] = LayerNorm(X[row] + Y[row]) * gamma + beta ; D = 1024
// ---------------------------------------------------------------------------
__global__ __launch_bounds__(256) void add_ln_kernel(
    const float* __restrict__ X, const float* __restrict__ Y,
    const float* __restrict__ gamma, const float* __restrict__ beta,
    float* __restrict__ Out)
{
    const int row = blockIdx.x;
    const int tid = threadIdx.x;
    __shared__ float red[256];

    const float* xr = X + (long)row * D_;
    const float* yr = Y + (long)row * D_;

    float v[4];
    float s = 0.f;
#pragma unroll
    for (int j = 0; j < 4; ++j) {
        v[j] = xr[tid + j*256] + yr[tid + j*256];
        s += v[j];
    }
    red[tid] = s; __syncthreads();
#pragma unroll
    for (int off = 128; off > 0; off >>= 1) {
        if (tid < off) red[tid] += red[tid+off];
        __syncthreads();
    }
    const float mean = red[0] * (1.0f / D_);
    __syncthreads();

    float s2 = 0.f;
#pragma unroll
    for (int j = 0; j < 4; ++j) { float dd = v[j] - mean; s2 += dd*dd; }
    red[tid] = s2; __syncthreads();
#pragma unroll
    for (int off = 128; off > 0; off >>= 1) {
        if (tid < off) red[tid] += red[tid+off];
        __syncthreads();
    }
    const float var = red[0] * (1.0f / D_);
    const float rs = rsqrtf(var + 1e-5f);

#pragma unroll
    for (int j = 0; j < 4; ++j) {
        const int c = tid + j*256;
        Out[(long)row * D_ + c] = (v[j] - mean) * rs * gamma[c] + beta[c];
    }
}

// ---------------------------------------------------------------------------
extern "C" void kernel_launch(void* const* d_in, const int* in_sizes, int n_in,
                              void* d_out, int out_size, void* d_ws, size_t ws_size,
                              hipStream_t stream)
{
    const int LAYER = 5;  // only the last layer's output survives (x=decoderInput bug)

    const float* decIn  = (const float*)d_in[0];
    const float* encOut = (const float*)d_in[1];
    const float* Wq1 = (const float*)d_in[2]  + (long)LAYER * H_ * D_ * DK_;
    const float* bq1 = (const float*)d_in[3]  + (long)LAYER * H_ * DK_;
    const float* Wk1 = (const float*)d_in[4]  + (long)LAYER * H_ * D_ * DK_;
    const float* bk1 = (const float*)d_in[5]  + (long)LAYER * H_ * DK_;
    const float* Wv1 = (const float*)d_in[6]  + (long)LAYER * H_ * D_ * DK_;
    const float* bv1 = (const float*)d_in[7]  + (long)LAYER * H_ * DK_;
    const float* Wq2 = (const float*)d_in[8]  + (long)LAYER * H_ * D_ * DK_;
    const float* bq2 = (const float*)d_in[9]  + (long)LAYER * H_ * DK_;
    const float* Wk2 = (const float*)d_in[10] + (long)LAYER * H_ * D_ * DK_;
    const float* bk2 = (const float*)d_in[11] + (long)LAYER * H_ * DK_;
    const float* Wv2 = (const float*)d_in[12] + (long)LAYER * H_ * D_ * DK_;
    const float* bv2 = (const float*)d_in[13] + (long)LAYER * H_ * DK_;
    const float* Wff1 = (const float*)d_in[14] + (long)LAYER * D_ * FF_;
    const float* bff1 = (const float*)d_in[15] + (long)LAYER * FF_;
    const float* Wff2 = (const float*)d_in[16] + (long)LAYER * FF_ * D_;
    const float* bff2 = (const float*)d_in[17] + (long)LAYER * D_;
    const float* gamma = (const float*)d_in[18];
    const float* beta  = (const float*)d_in[19];

    // workspace carve-up (bytes)
    char* w = (char*)d_ws;
    __hip_bfloat16* Qb = (__hip_bfloat16*)w;             w += (long)H_*S_*DK_*2;   // 4 MB
    __hip_bfloat16* Kb = (__hip_bfloat16*)w;             w += (long)H_*SE_*DK_*2;  // 4 MB
    __hip_bfloat16* Vt = (__hip_bfloat16*)w;             w += (long)H_*DK_*SE_*2;  // 4 MB
    float* attn = (float*)w;                             w += (long)S_*D_*4;       // 8 MB
    float* h1   = (float*)w;                             w += (long)S_*D_*4;
    float* h2   = (float*)w;                             w += (long)S_*D_*4;
    float* ffh  = (float*)w;                             w += (long)S_*FF_*4;      // 32 MB
    float* ff2  = (float*)w;                             w += (long)S_*D_*4;

    float* outp = (float*)d_out;
    const dim3 blk(256);
    const dim3 ablk(128);

    // ---------------- self attention (masked) ----------------
    {
        dim3 grid(DK_/64, S_/64, H_);
        gemm_kernel<<<grid, blk, 0, stream>>>(decIn, Wq1, bq1, Qb,
            S_, DK_, D_, D_, DK_, DK_, 0L, (long)D_*DK_, (long)DK_, (long)S_*DK_, 0, 1);
        gemm_kernel<<<grid, blk, 0, stream>>>(decIn, Wk1, bk1, Kb,
            S_, DK_, D_, D_, DK_, DK_, 0L, (long)D_*DK_, (long)DK_, (long)S_*DK_, 0, 1);
        gemm_kernel<<<grid, blk, 0, stream>>>(decIn, Wv1, bv1, Vt,
            S_, DK_, D_, D_, DK_, S_, 0L, (long)D_*DK_, (long)DK_, (long)DK_*S_, 0, 2);
    }
    mfma_attn_kernel<<<dim3(S_/32, H_), ablk, 0, stream>>>(Qb, Kb, Vt, attn, S_, 1);
    add_ln_kernel<<<dim3(S_), blk, 0, stream>>>(decIn, attn, gamma, beta, h1);

    // ---------------- cross attention (unmasked) ----------------
    {
        dim3 grid(DK_/64, S_/64, H_);
        gemm_kernel<<<grid, blk, 0, stream>>>(h1, Wq2, bq2, Qb,
            S_, DK_, D_, D_, DK_, DK_, 0L, (long)D_*DK_, (long)DK_, (long)S_*DK_, 0, 1);
        dim3 gridE(DK_/64, SE_/64, H_);
        gemm_kernel<<<gridE, blk, 0, stream>>>(encOut, Wk2, bk2, Kb,
            SE_, DK_, D_, D_, DK_, DK_, 0L, (long)D_*DK_, (long)DK_, (long)SE_*DK_, 0, 1);
        gemm_kernel<<<gridE, blk, 0, stream>>>(encOut, Wv2, bv2, Vt,
            SE_, DK_, D_, D_, DK_, SE_, 0L, (long)D_*DK_, (long)DK_, (long)DK_*SE_, 0, 2);
    }
    mfma_attn_kernel<<<dim3(S_/32, H_), ablk, 0, stream>>>(Qb, Kb, Vt, attn, SE_, 0);
    add_ln_kernel<<<dim3(S_), blk, 0, stream>>>(h1, attn, gamma, beta, h2);

    // ---------------- feed-forward ----------------
    gemm_kernel<<<dim3(FF_/64, S_/64, 1), blk, 0, stream>>>(h2, Wff1, bff1, ffh,
        S_, FF_, D_, D_, FF_, FF_, 0L, 0L, 0L, 0L, 1, 0);
    gemm_kernel<<<dim3(D_/64, S_/64, 1), blk, 0, stream>>>(ffh, Wff2, bff2, ff2,
        S_, D_, FF_, FF_, D_, D_, 0L, 0L, 0L, 0L, 0, 0);

    add_ln_kernel<<<dim3(S_), blk, 0, stream>>>(h2, ff2, gamma, beta, outp);
}

// Round 4
// 846.246 us; speedup vs baseline: 7.0222x; 2.2826x over previous
//
#include <hip/hip_runtime.h>
#include <hip/hip_bf16.h>
#include <math.h>

#define S_ 2048
#define SE_ 2048
#define D_ 1024
#define H_ 8
#define DK_ 128
#define FF_ 4096

typedef short bf16x8 __attribute__((ext_vector_type(8)));
typedef unsigned short u16x8 __attribute__((ext_vector_type(8)));
typedef float f32x4 __attribute__((ext_vector_type(4)));

__device__ __forceinline__ unsigned short bf16_bits(float x) {
    __hip_bfloat16 h = __float2bfloat16(x);
    return *reinterpret_cast<unsigned short*>(&h);
}

__device__ __forceinline__ void load_lds16(const void* gptr, void* lptr) {
    __builtin_amdgcn_global_load_lds(
        (const __attribute__((address_space(1))) unsigned int*)gptr,
        (__attribute__((address_space(3))) unsigned int*)lptr,
        16, 0, 0);
}

// ---------------------------------------------------------------------------
// bf16 MFMA GEMM (m97 structure): C[M,N] = A[M,K] @ Bt[N,K]^T + bias.
// 128x128 tile, BK=32, 256 threads = 4 waves (2x2), 4x4 frags of 16x16x32.
// Staging via global_load_lds width=16 into linear LDS [128][32] bf16.
// mode: 0 = f32 store C[r*ldc+c]; 1 = bf16 store; 2 = bf16 transposed
//       store C[c*ldc+r] (for V^T).
// Frag layouts (HW-verified via round-3 attn): A m=lane&15,k=8g+j;
// B n=lane&15,k=8g+j; D col=lane&15,row=4g+reg.
// ---------------------------------------------------------------------------
__global__ __launch_bounds__(256) void gemm_bf16_kernel(
    const __hip_bfloat16* __restrict__ A, const __hip_bfloat16* __restrict__ Bt,
    const float* __restrict__ bias, void* __restrict__ C,
    int M, int N, int K, int ldc, int relu, int mode)
{
    __shared__ short As[128 * 32];
    __shared__ short Bs[128 * 32];

    const int tid  = threadIdx.x;
    const int w    = tid >> 6;
    const int lane = tid & 63;
    const int n    = lane & 15;
    const int g    = lane >> 4;
    const int wr   = w >> 1;
    const int wc   = w & 1;
    const int rowBase = blockIdx.y * 128;
    const int colBase = blockIdx.x * 128;

    f32x4 acc[4][4];
#pragma unroll
    for (int mi = 0; mi < 4; ++mi)
#pragma unroll
        for (int ni = 0; ni < 4; ++ni) acc[mi][ni] = f32x4{0.f, 0.f, 0.f, 0.f};

    for (int k0 = 0; k0 < K; k0 += 32) {
        // ---- stage A,B tiles (8KB each) via global_load_lds x16B ----
#pragma unroll
        for (int i = 0; i < 2; ++i) {
            const int slot0 = (i * 4 + w) * 64;          // wave-uniform base slot
            const int slot  = slot0 + lane;
            const int r = slot >> 2, q = slot & 3;       // tile row, 8-elem chunk
            load_lds16(A  + (long)(rowBase + r) * K + k0 + q * 8,
                       (char*)As + slot0 * 16);
            load_lds16(Bt + (long)(colBase + r) * K + k0 + q * 8,
                       (char*)Bs + slot0 * 16);
        }
        __syncthreads();   // drains vmcnt -> staged data visible

        bf16x8 af[4], bf[4];
#pragma unroll
        for (int mi = 0; mi < 4; ++mi)
            af[mi] = *reinterpret_cast<const bf16x8*>(
                (const char*)As + (wr * 64 + mi * 16 + n) * 64 + g * 16);
#pragma unroll
        for (int ni = 0; ni < 4; ++ni)
            bf[ni] = *reinterpret_cast<const bf16x8*>(
                (const char*)Bs + (wc * 64 + ni * 16 + n) * 64 + g * 16);

#pragma unroll
        for (int mi = 0; mi < 4; ++mi)
#pragma unroll
            for (int ni = 0; ni < 4; ++ni)
                acc[mi][ni] = __builtin_amdgcn_mfma_f32_16x16x32_bf16(
                    af[mi], bf[ni], acc[mi][ni], 0, 0, 0);
        __syncthreads();   // protect LDS before next stage
    }

#pragma unroll
    for (int mi = 0; mi < 4; ++mi)
#pragma unroll
        for (int ni = 0; ni < 4; ++ni)
#pragma unroll
            for (int r2 = 0; r2 < 4; ++r2) {
                const int row = rowBase + wr * 64 + mi * 16 + 4 * g + r2;
                const int col = colBase + wc * 64 + ni * 16 + n;
                float v = acc[mi][ni][r2] + bias[col];
                if (relu) v = fmaxf(v, 0.f);
                if (mode == 0)
                    ((float*)C)[(long)row * ldc + col] = v;
                else if (mode == 1)
                    ((__hip_bfloat16*)C)[(long)row * ldc + col] = __float2bfloat16(v);
                else
                    ((__hip_bfloat16*)C)[(long)col * ldc + row] = __float2bfloat16(v);
            }
}

// ---------------------------------------------------------------------------
// fp32 -> bf16 convert, 8 elems/thread.
// ---------------------------------------------------------------------------
__global__ __launch_bounds__(256) void cvt_bf16_kernel(
    const float* __restrict__ in, __hip_bfloat16* __restrict__ out, int n8)
{
    const int i = blockIdx.x * 256 + threadIdx.x;
    if (i >= n8) return;
    const float4* p = reinterpret_cast<const float4*>(in) + (long)i * 2;
    float4 a = p[0], b = p[1];
    u16x8 o;
    o[0] = bf16_bits(a.x); o[1] = bf16_bits(a.y);
    o[2] = bf16_bits(a.z); o[3] = bf16_bits(a.w);
    o[4] = bf16_bits(b.x); o[5] = bf16_bits(b.y);
    o[6] = bf16_bits(b.z); o[7] = bf16_bits(b.w);
    *(reinterpret_cast<u16x8*>(out) + i) = o;
}

// ---------------------------------------------------------------------------
// Tiled transpose + convert: out[c*R + r] = bf16(in[r*C + c]), batched over z.
// Block 256 = 32x8, tile 32x32, LDS padded.
// ---------------------------------------------------------------------------
__global__ __launch_bounds__(256) void tcvt_kernel(
    const float* __restrict__ in, __hip_bfloat16* __restrict__ out,
    int R, int C, long sIn, long sOut)
{
    in  += (long)blockIdx.z * sIn;
    out += (long)blockIdx.z * sOut;
    __shared__ float t[32][33];
    const int bx = blockIdx.x * 32;   // c-base
    const int by = blockIdx.y * 32;   // r-base
    const int tx = threadIdx.x & 31;
    const int ty = threadIdx.x >> 5;  // 0..7
#pragma unroll
    for (int j = 0; j < 4; ++j)
        t[ty + j * 8][tx] = in[(long)(by + ty + j * 8) * C + bx + tx];
    __syncthreads();
#pragma unroll
    for (int j = 0; j < 4; ++j)
        out[(long)(bx + ty + j * 8) * R + by + tx] =
            __float2bfloat16(t[tx][ty + j * 8]);
}

// ---------------------------------------------------------------------------
// MFMA flash attention (unchanged structure; Q/K in [S][H*DK] layout now).
// Q,K: [S][1024] bf16; Vt: [H*128][T] bf16; O: [S][H*128] f32.
// scores = (Q.K^T)/1024 per reference.
// ---------------------------------------------------------------------------
__global__ __launch_bounds__(128) void mfma_attn_kernel(
    const __hip_bfloat16* __restrict__ Q, const __hip_bfloat16* __restrict__ K,
    const __hip_bfloat16* __restrict__ Vt, float* __restrict__ O,
    int T, int masked)
{
    const int h    = blockIdx.y;
    const int w    = threadIdx.x >> 6;
    const int lane = threadIdx.x & 63;
    const int n    = lane & 15;
    const int g    = lane >> 4;
    const int qw   = blockIdx.x * 32 + w * 16;

    __shared__ short P_lds[2][16][40];

    const __hip_bfloat16* Qh = Q  + h * DK_;
    const __hip_bfloat16* Kh = K  + h * DK_;
    const __hip_bfloat16* Vh = Vt + (long)h * DK_ * T;

    bf16x8 qf[4];
#pragma unroll
    for (int kc = 0; kc < 4; ++kc)
        qf[kc] = *reinterpret_cast<const bf16x8*>(
            Qh + (long)(qw + n) * (H_ * DK_) + kc * 32 + g * 8);

    f32x4 o[8];
#pragma unroll
    for (int vt = 0; vt < 8; ++vt) o[vt] = f32x4{0.f, 0.f, 0.f, 0.f};
    float mrow[4] = {-INFINITY, -INFINITY, -INFINITY, -INFINITY};
    float lrow[4] = {0.f, 0.f, 0.f, 0.f};

    const int nch = masked ? ((qw + 47) >> 5) : (T >> 5);

    bf16x8 kf[2][4], vf[8];
#pragma unroll
    for (int tt = 0; tt < 2; ++tt)
#pragma unroll
        for (int kc = 0; kc < 4; ++kc)
            kf[tt][kc] = *reinterpret_cast<const bf16x8*>(
                Kh + (long)(tt * 16 + n) * (H_ * DK_) + kc * 32 + g * 8);
#pragma unroll
    for (int vt = 0; vt < 8; ++vt)
        vf[vt] = *reinterpret_cast<const bf16x8*>(
            Vh + (long)(vt * 16 + n) * T + g * 8);

    for (int i = 0; i < nch; ++i) {
        const int t0 = i * 32;
        const int t1 = (i + 1 < nch) ? (t0 + 32) : t0;

        f32x4 s0 = {0.f, 0.f, 0.f, 0.f}, s1 = {0.f, 0.f, 0.f, 0.f};
#pragma unroll
        for (int kc = 0; kc < 4; ++kc) {
            s0 = __builtin_amdgcn_mfma_f32_16x16x32_bf16(qf[kc], kf[0][kc], s0, 0, 0, 0);
            s1 = __builtin_amdgcn_mfma_f32_16x16x32_bf16(qf[kc], kf[1][kc], s1, 0, 0, 0);
        }

#pragma unroll
        for (int tt = 0; tt < 2; ++tt)
#pragma unroll
            for (int kc = 0; kc < 4; ++kc)
                kf[tt][kc] = *reinterpret_cast<const bf16x8*>(
                    Kh + (long)(t1 + tt * 16 + n) * (H_ * DK_) + kc * 32 + g * 8);

        const bool needmask = masked && (t0 + 31 > qw);
        float corr[4];
#pragma unroll
        for (int r = 0; r < 4; ++r) {
            float a = s0[r] * (1.0f / 1024.0f);
            float b = s1[r] * (1.0f / 1024.0f);
            if (needmask) {
                const int qg = qw + 4 * g + r;
                if (t0 + n > qg)      a = -INFINITY;
                if (t0 + 16 + n > qg) b = -INFINITY;
            }
            float mx = fmaxf(a, b);
            mx = fmaxf(mx, __shfl_xor(mx, 1));
            mx = fmaxf(mx, __shfl_xor(mx, 2));
            mx = fmaxf(mx, __shfl_xor(mx, 4));
            mx = fmaxf(mx, __shfl_xor(mx, 8));
            const float mnew = fmaxf(mrow[r], mx);
            const float c  = __expf(mrow[r] - mnew);
            const float pa = __expf(a - mnew);
            const float pb = __expf(b - mnew);
            float rs = pa + pb;
            rs += __shfl_xor(rs, 1);
            rs += __shfl_xor(rs, 2);
            rs += __shfl_xor(rs, 4);
            rs += __shfl_xor(rs, 8);
            lrow[r] = lrow[r] * c + rs;
            mrow[r] = mnew;
            corr[r] = c;
            P_lds[w][4 * g + r][n]      = (short)bf16_bits(pa);
            P_lds[w][4 * g + r][16 + n] = (short)bf16_bits(pb);
        }

#pragma unroll
        for (int vt = 0; vt < 8; ++vt)
#pragma unroll
            for (int r = 0; r < 4; ++r) o[vt][r] *= corr[r];

        bf16x8 pfrag = *reinterpret_cast<const bf16x8*>(&P_lds[w][n][g * 8]);
#pragma unroll
        for (int vt = 0; vt < 8; ++vt)
            o[vt] = __builtin_amdgcn_mfma_f32_16x16x32_bf16(pfrag, vf[vt], o[vt], 0, 0, 0);

#pragma unroll
        for (int vt = 0; vt < 8; ++vt)
            vf[vt] = *reinterpret_cast<const bf16x8*>(
                Vh + (long)(vt * 16 + n) * T + t1 + g * 8);
    }

#pragma unroll
    for (int vt = 0; vt < 8; ++vt)
#pragma unroll
        for (int r = 0; r < 4; ++r)
            O[(long)(qw + 4 * g + r) * (H_ * DK_) + h * DK_ + vt * 16 + n] =
                o[vt][r] / lrow[r];
}

// ---------------------------------------------------------------------------
// out = LayerNorm(X + Y) * gamma + beta; optional bf16 copy of the output.
// ---------------------------------------------------------------------------
__global__ __launch_bounds__(256) void add_ln_kernel(
    const float* __restrict__ X, const float* __restrict__ Y,
    const float* __restrict__ gamma, const float* __restrict__ beta,
    float* __restrict__ Out, __hip_bfloat16* __restrict__ OutBf)
{
    const int row = blockIdx.x;
    const int tid = threadIdx.x;
    __shared__ float red[256];

    const float* xr = X + (long)row * D_;
    const float* yr = Y + (long)row * D_;

    float v[4];
    float s = 0.f;
#pragma unroll
    for (int j = 0; j < 4; ++j) {
        v[j] = xr[tid + j * 256] + yr[tid + j * 256];
        s += v[j];
    }
    red[tid] = s; __syncthreads();
#pragma unroll
    for (int off = 128; off > 0; off >>= 1) {
        if (tid < off) red[tid] += red[tid + off];
        __syncthreads();
    }
    const float mean = red[0] * (1.0f / D_);
    __syncthreads();

    float s2 = 0.f;
#pragma unroll
    for (int j = 0; j < 4; ++j) { float dd = v[j] - mean; s2 += dd * dd; }
    red[tid] = s2; __syncthreads();
#pragma unroll
    for (int off = 128; off > 0; off >>= 1) {
        if (tid < off) red[tid] += red[tid + off];
        __syncthreads();
    }
    const float var = red[0] * (1.0f / D_);
    const float rs = rsqrtf(var + 1e-5f);

#pragma unroll
    for (int j = 0; j < 4; ++j) {
        const int c = tid + j * 256;
        const float ov = (v[j] - mean) * rs * gamma[c] + beta[c];
        Out[(long)row * D_ + c] = ov;
        if (OutBf) OutBf[(long)row * D_ + c] = __float2bfloat16(ov);
    }
}

// ---------------------------------------------------------------------------
extern "C" void kernel_launch(void* const* d_in, const int* in_sizes, int n_in,
                              void* d_out, int out_size, void* d_ws, size_t ws_size,
                              hipStream_t stream)
{
    const int LAYER = 5;  // only the last layer's output survives (x=decoderInput bug)

    const float* decIn  = (const float*)d_in[0];
    const float* encOut = (const float*)d_in[1];
    const float* Wq1 = (const float*)d_in[2]  + (long)LAYER * H_ * D_ * DK_;
    const float* bq1 = (const float*)d_in[3]  + (long)LAYER * H_ * DK_;
    const float* Wk1 = (const float*)d_in[4]  + (long)LAYER * H_ * D_ * DK_;
    const float* bk1 = (const float*)d_in[5]  + (long)LAYER * H_ * DK_;
    const float* Wv1 = (const float*)d_in[6]  + (long)LAYER * H_ * D_ * DK_;
    const float* bv1 = (const float*)d_in[7]  + (long)LAYER * H_ * DK_;
    const float* Wq2 = (const float*)d_in[8]  + (long)LAYER * H_ * D_ * DK_;
    const float* bq2 = (const float*)d_in[9]  + (long)LAYER * H_ * DK_;
    const float* Wk2 = (const float*)d_in[10] + (long)LAYER * H_ * D_ * DK_;
    const float* bk2 = (const float*)d_in[11] + (long)LAYER * H_ * DK_;
    const float* Wv2 = (const float*)d_in[12] + (long)LAYER * H_ * D_ * DK_;
    const float* bv2 = (const float*)d_in[13] + (long)LAYER * H_ * DK_;
    const float* Wff1 = (const float*)d_in[14] + (long)LAYER * D_ * FF_;
    const float* bff1 = (const float*)d_in[15] + (long)LAYER * FF_;
    const float* Wff2 = (const float*)d_in[16] + (long)LAYER * FF_ * D_;
    const float* bff2 = (const float*)d_in[17] + (long)LAYER * D_;
    const float* gamma = (const float*)d_in[18];
    const float* beta  = (const float*)d_in[19];

    // ---- workspace carve-up ----
    const long MB = 1024 * 1024;
    char* p = (char*)d_ws;
    __hip_bfloat16* Qb    = (__hip_bfloat16*)p; p += 4 * MB;   // [2048][1024]
    __hip_bfloat16* Kb    = (__hip_bfloat16*)p; p += 4 * MB;   // [2048][1024]
    __hip_bfloat16* Vt    = (__hip_bfloat16*)p; p += 4 * MB;   // [1024][2048]
    float*          attnb = (float*)p;          p += 8 * MB;   // [2048][1024] f32
    __hip_bfloat16* dec_bf = (__hip_bfloat16*)p; p += 4 * MB;
    __hip_bfloat16* enc_bf = (__hip_bfloat16*)p; p += 4 * MB;
    __hip_bfloat16* Btq   = (__hip_bfloat16*)p; p += 2 * MB;   // [1024][1024]
    __hip_bfloat16* Btk   = (__hip_bfloat16*)p; p += 2 * MB;
    __hip_bfloat16* Btv   = (__hip_bfloat16*)p; p += 2 * MB;
    float*          h1    = (float*)p;          p += 8 * MB;
    __hip_bfloat16* h1_bf = (__hip_bfloat16*)p; p += 4 * MB;
    float*          h2    = (float*)p;          p += 8 * MB;
    __hip_bfloat16* h2_bf = (__hip_bfloat16*)p; p += 4 * MB;
    __hip_bfloat16* ffh   = (__hip_bfloat16*)p; p += 16 * MB;  // [2048][4096]
    float*          ff2   = (float*)p;          p += 8 * MB;
    // FF weight transposes alias attention-phase buffers (free by then):
    __hip_bfloat16* Wff1t = Qb;   // 8 MB over Qb+Kb   [4096][1024]
    __hip_bfloat16* Wff2t = Vt;   // 8 MB over Vt+attnb[0:4MB]  [1024][4096]

    float* outp = (float*)d_out;
    const dim3 blk256(256);

    // ---- input converts ----
    cvt_bf16_kernel<<<dim3(S_ * D_ / 8 / 256), blk256, 0, stream>>>(decIn, dec_bf, S_ * D_ / 8);
    cvt_bf16_kernel<<<dim3(SE_ * D_ / 8 / 256), blk256, 0, stream>>>(encOut, enc_bf, SE_ * D_ / 8);

    // ---- self-attention weight transposes: Bt[h*128+k][d] = W[h][d][k] ----
    const dim3 tgridP(DK_ / 32, D_ / 32, H_);
    tcvt_kernel<<<tgridP, blk256, 0, stream>>>(Wq1, Btq, D_, DK_, (long)D_ * DK_, (long)DK_ * D_);
    tcvt_kernel<<<tgridP, blk256, 0, stream>>>(Wk1, Btk, D_, DK_, (long)D_ * DK_, (long)DK_ * D_);
    tcvt_kernel<<<tgridP, blk256, 0, stream>>>(Wv1, Btv, D_, DK_, (long)D_ * DK_, (long)DK_ * D_);

    // ---- self attention ----
    const dim3 gproj(D_ / 128, S_ / 128);   // N=1024, M=2048
    gemm_bf16_kernel<<<gproj, blk256, 0, stream>>>(dec_bf, Btq, bq1, Qb, S_, D_, D_, D_, 0, 1);
    gemm_bf16_kernel<<<gproj, blk256, 0, stream>>>(dec_bf, Btk, bk1, Kb, S_, D_, D_, D_, 0, 1);
    gemm_bf16_kernel<<<gproj, blk256, 0, stream>>>(dec_bf, Btv, bv1, Vt, S_, D_, D_, S_, 0, 2);
    mfma_attn_kernel<<<dim3(S_ / 32, H_), dim3(128), 0, stream>>>(Qb, Kb, Vt, attnb, S_, 1);
    add_ln_kernel<<<dim3(S_), blk256, 0, stream>>>(decIn, attnb, gamma, beta, h1, h1_bf);

    // ---- cross attention ----
    tcvt_kernel<<<tgridP, blk256, 0, stream>>>(Wq2, Btq, D_, DK_, (long)D_ * DK_, (long)DK_ * D_);
    tcvt_kernel<<<tgridP, blk256, 0, stream>>>(Wk2, Btk, D_, DK_, (long)D_ * DK_, (long)DK_ * D_);
    tcvt_kernel<<<tgridP, blk256, 0, stream>>>(Wv2, Btv, D_, DK_, (long)D_ * DK_, (long)DK_ * D_);
    gemm_bf16_kernel<<<gproj, blk256, 0, stream>>>(h1_bf, Btq, bq2, Qb, S_, D_, D_, D_, 0, 1);
    gemm_bf16_kernel<<<gproj, blk256, 0, stream>>>(enc_bf, Btk, bk2, Kb, SE_, D_, D_, D_, 0, 1);
    gemm_bf16_kernel<<<gproj, blk256, 0, stream>>>(enc_bf, Btv, bv2, Vt, SE_, D_, D_, SE_, 0, 2);
    mfma_attn_kernel<<<dim3(S_ / 32, H_), dim3(128), 0, stream>>>(Qb, Kb, Vt, attnb, SE_, 0);
    add_ln_kernel<<<dim3(S_), blk256, 0, stream>>>(h1, attnb, gamma, beta, h2, h2_bf);

    // ---- feed-forward (FF weight transposes aliased over Qb/Kb and Vt/attnb) ----
    tcvt_kernel<<<dim3(FF_ / 32, D_ / 32, 1), blk256, 0, stream>>>(Wff1, Wff1t, D_, FF_, 0L, 0L);
    tcvt_kernel<<<dim3(D_ / 32, FF_ / 32, 1), blk256, 0, stream>>>(Wff2, Wff2t, FF_, D_, 0L, 0L);
    gemm_bf16_kernel<<<dim3(FF_ / 128, S_ / 128), blk256, 0, stream>>>(
        h2_bf, Wff1t, bff1, ffh, S_, FF_, D_, FF_, 1, 1);
    gemm_bf16_kernel<<<dim3(D_ / 128, S_ / 128), blk256, 0, stream>>>(
        ffh, Wff2t, bff2, ff2, S_, D_, FF_, D_, 0, 0);

    add_ln_kernel<<<dim3(S_), blk256, 0, stream>>>(h2, ff2, gamma, beta, outp, (  __hip_bfloat16*)nullptr);
}